// Round 4
// baseline (69.832 us; speedup 1.0000x reference)
//
#include <hip/hip_runtime.h>
#include <hip/hip_fp16.h>

#define SAMPLES 32
#define ELEMS_PER_SAMPLE (256 * 64 * 64)              // 1048576
#define VEC4_PER_SAMPLE (ELEMS_PER_SAMPLE / 4)        // 262144
#define BLOCKS_PER_SAMPLE 64
#define THREADS 256
#define GRID (SAMPLES * BLOCKS_PER_SAMPLE)            // 2048
#define ITERS (VEC4_PER_SAMPLE / (BLOCKS_PER_SAMPLE * THREADS))  // 16

#define BETA 2.0f
#define EPS 1e-5f

typedef float f32x4 __attribute__((ext_vector_type(4)));
typedef _Float16 f16x4 __attribute__((ext_vector_type(4)));

// fp16 teacher copy: 32 * 1048576 * 2 B = 64 MiB
#define TC_BYTES ((size_t)SAMPLES * ELEMS_PER_SAMPLE * 2)

__device__ __forceinline__ float wave_reduce_sum(float v) {
#pragma unroll
    for (int off = 32; off > 0; off >>= 1)
        v += __shfl_down(v, off, 64);
    return v;
}

__device__ __forceinline__ float smooth_l1(float d) {
    return (d <= BETA) ? (0.25f * d * d) : (d - 1.0f);
}

// ================= compressed path =================
// Kernel 1: read teacher f32 (nt), write fp16 copy (regular -> L3),
//           emit per-block (sum, sumsq).
__global__ __launch_bounds__(THREADS) void kd_stats_c_kernel(
    const f32x4* __restrict__ t, f16x4* __restrict__ tc,
    float* __restrict__ stats) {
    const size_t base = (size_t)blockIdx.x * (THREADS * ITERS);

    float sum = 0.0f, sumsq = 0.0f;
#pragma unroll
    for (int i = 0; i < ITERS; ++i) {
        const size_t idx = base + i * THREADS + threadIdx.x;
        f32x4 v = __builtin_nontemporal_load(t + idx);
        sum += v.x + v.y + v.z + v.w;
        sumsq += v.x * v.x + v.y * v.y + v.z * v.z + v.w * v.w;
        f16x4 h;
        h.x = (_Float16)v.x; h.y = (_Float16)v.y;
        h.z = (_Float16)v.z; h.w = (_Float16)v.w;
        tc[idx] = h;
    }

    const int lane = threadIdx.x & 63;
    const int wid = threadIdx.x >> 6;
    sum = wave_reduce_sum(sum);
    sumsq = wave_reduce_sum(sumsq);

    __shared__ float sm[2 * (THREADS / 64)];
    if (lane == 0) {
        sm[wid] = sum;
        sm[(THREADS / 64) + wid] = sumsq;
    }
    __syncthreads();
    if (threadIdx.x == 0) {
        stats[2 * blockIdx.x]     = sm[0] + sm[1] + sm[2] + sm[3];
        stats[2 * blockIdx.x + 1] = sm[4] + sm[5] + sm[6] + sm[7];
    }
}

// Kernel 2: stats from partials; read fp16 teacher copy (L3-hot) +
//           f32 student (nt); per-block loss partial.
__global__ __launch_bounds__(THREADS) void kd_loss_c_kernel(
    const f16x4* __restrict__ tc, const f32x4* __restrict__ st,
    const float* __restrict__ stats, float* __restrict__ lpart) {
    const int s = blockIdx.x / BLOCKS_PER_SAMPLE;
    const int lane = threadIdx.x & 63;
    const int wid = threadIdx.x >> 6;

    float psum   = stats[2 * (s * BLOCKS_PER_SAMPLE + lane)];
    float psumsq = stats[2 * (s * BLOCKS_PER_SAMPLE + lane) + 1];
    psum = wave_reduce_sum(psum);
    psumsq = wave_reduce_sum(psumsq);
    psum = __shfl(psum, 0, 64);
    psumsq = __shfl(psumsq, 0, 64);

    const float inv_n = 1.0f / (float)ELEMS_PER_SAMPLE;
    const float mean = psum * inv_n;
    const float var = psumsq * inv_n - mean * mean;
    const float rstd = rsqrtf(var + EPS);

    const size_t base = (size_t)blockIdx.x * (THREADS * ITERS);

    float acc = 0.0f;
#pragma unroll
    for (int i = 0; i < ITERS; ++i) {
        const size_t idx = base + i * THREADS + threadIdx.x;
        f16x4 h = tc[idx];
        f32x4 sv = __builtin_nontemporal_load(st + idx);

        float d0 = fabsf(((float)h.x - mean) * rstd - sv.x);
        float d1 = fabsf(((float)h.y - mean) * rstd - sv.y);
        float d2 = fabsf(((float)h.z - mean) * rstd - sv.z);
        float d3 = fabsf(((float)h.w - mean) * rstd - sv.w);

        acc += smooth_l1(d0) + smooth_l1(d1) + smooth_l1(d2) + smooth_l1(d3);
    }

    acc = wave_reduce_sum(acc);
    __shared__ float sm[THREADS / 64];
    if (lane == 0) sm[wid] = acc;
    __syncthreads();
    if (threadIdx.x == 0)
        lpart[blockIdx.x] = sm[0] + sm[1] + sm[2] + sm[3];
}

// ================= fallback path (no scratch copy) =================
__global__ __launch_bounds__(THREADS) void kd_stats_kernel(
    const f32x4* __restrict__ t, float* __restrict__ stats) {
    const size_t base = (size_t)blockIdx.x * (THREADS * ITERS);
    float sum = 0.0f, sumsq = 0.0f;
#pragma unroll
    for (int i = 0; i < ITERS; ++i) {
        f32x4 v = t[base + i * THREADS + threadIdx.x];
        sum += v.x + v.y + v.z + v.w;
        sumsq += v.x * v.x + v.y * v.y + v.z * v.z + v.w * v.w;
    }
    const int lane = threadIdx.x & 63;
    const int wid = threadIdx.x >> 6;
    sum = wave_reduce_sum(sum);
    sumsq = wave_reduce_sum(sumsq);
    __shared__ float sm[2 * (THREADS / 64)];
    if (lane == 0) {
        sm[wid] = sum;
        sm[(THREADS / 64) + wid] = sumsq;
    }
    __syncthreads();
    if (threadIdx.x == 0) {
        stats[2 * blockIdx.x]     = sm[0] + sm[1] + sm[2] + sm[3];
        stats[2 * blockIdx.x + 1] = sm[4] + sm[5] + sm[6] + sm[7];
    }
}

__global__ __launch_bounds__(THREADS) void kd_loss_kernel(
    const f32x4* __restrict__ t, const f32x4* __restrict__ st,
    const float* __restrict__ stats, float* __restrict__ lpart) {
    const int s = blockIdx.x / BLOCKS_PER_SAMPLE;
    const int lane = threadIdx.x & 63;
    const int wid = threadIdx.x >> 6;

    float psum   = stats[2 * (s * BLOCKS_PER_SAMPLE + lane)];
    float psumsq = stats[2 * (s * BLOCKS_PER_SAMPLE + lane) + 1];
    psum = wave_reduce_sum(psum);
    psumsq = wave_reduce_sum(psumsq);
    psum = __shfl(psum, 0, 64);
    psumsq = __shfl(psumsq, 0, 64);

    const float inv_n = 1.0f / (float)ELEMS_PER_SAMPLE;
    const float mean = psum * inv_n;
    const float var = psumsq * inv_n - mean * mean;
    const float rstd = rsqrtf(var + EPS);

    const size_t base = (size_t)blockIdx.x * (THREADS * ITERS);
    float acc = 0.0f;
#pragma unroll
    for (int i = 0; i < ITERS; ++i) {
        const size_t idx = base + i * THREADS + threadIdx.x;
        f32x4 tv = t[idx];
        f32x4 sv = __builtin_nontemporal_load(st + idx);
        float d0 = fabsf((tv.x - mean) * rstd - sv.x);
        float d1 = fabsf((tv.y - mean) * rstd - sv.y);
        float d2 = fabsf((tv.z - mean) * rstd - sv.z);
        float d3 = fabsf((tv.w - mean) * rstd - sv.w);
        acc += smooth_l1(d0) + smooth_l1(d1) + smooth_l1(d2) + smooth_l1(d3);
    }

    acc = wave_reduce_sum(acc);
    __shared__ float sm[THREADS / 64];
    if (lane == 0) sm[wid] = acc;
    __syncthreads();
    if (threadIdx.x == 0)
        lpart[blockIdx.x] = sm[0] + sm[1] + sm[2] + sm[3];
}

// ================= final reduce =================
__global__ __launch_bounds__(THREADS) void kd_final_kernel(
    const float* __restrict__ lpart, float* __restrict__ out) {
    float acc = 0.0f;
#pragma unroll
    for (int i = 0; i < GRID / THREADS; ++i)  // 8
        acc += lpart[i * THREADS + threadIdx.x];
    const int lane = threadIdx.x & 63;
    const int wid = threadIdx.x >> 6;
    acc = wave_reduce_sum(acc);
    __shared__ float sm[THREADS / 64];
    if (lane == 0) sm[wid] = acc;
    __syncthreads();
    if (threadIdx.x == 0)
        out[0] = (sm[0] + sm[1] + sm[2] + sm[3]) * (1.0f / (float)SAMPLES);
}

extern "C" void kernel_launch(void* const* d_in, const int* in_sizes, int n_in,
                              void* d_out, int out_size, void* d_ws,
                              size_t ws_size, hipStream_t stream) {
    const float* teacher = (const float*)d_in[0];
    const float* student = (const float*)d_in[1];
    float* out = (float*)d_out;

    const size_t need = TC_BYTES + (size_t)(3 * GRID) * sizeof(float);
    if (ws_size >= need) {
        f16x4* tc = (f16x4*)d_ws;
        float* stats = (float*)((char*)d_ws + TC_BYTES);
        float* lpart = stats + 2 * GRID;

        kd_stats_c_kernel<<<GRID, THREADS, 0, stream>>>(
            (const f32x4*)teacher, tc, stats);
        kd_loss_c_kernel<<<GRID, THREADS, 0, stream>>>(
            tc, (const f32x4*)student, stats, lpart);
        kd_final_kernel<<<1, THREADS, 0, stream>>>(lpart, out);
    } else {
        float* stats = (float*)d_ws;
        float* lpart = stats + 2 * GRID;
        kd_stats_kernel<<<GRID, THREADS, 0, stream>>>(
            (const f32x4*)teacher, stats);
        kd_loss_kernel<<<GRID, THREADS, 0, stream>>>(
            (const f32x4*)teacher, (const f32x4*)student, stats, lpart);
        kd_final_kernel<<<1, THREADS, 0, stream>>>(lpart, out);
    }
}